// Round 5
// baseline (1325.857 us; speedup 1.0000x reference)
//
#include <hip/hip_runtime.h>
#include <stdint.h>

// ---------------- problem constants ----------------
constexpr int TT = 128;    // time steps
constexpr int BB = 256;    // batch
constexpr int LL = 1024;   // hidden dim
constexpr int NG = 4096;   // 4 gates * LL
constexpr int VV = 95;     // vocab

typedef short bf16x8 __attribute__((ext_vector_type(8)));
typedef float f32x4  __attribute__((ext_vector_type(4)));

typedef __attribute__((address_space(1))) const uint32_t gu32;
typedef __attribute__((address_space(3))) uint32_t lu32;

__device__ __forceinline__ unsigned short f2bf(float f) {
    unsigned int u = __builtin_bit_cast(unsigned int, f);
    unsigned int r = (u + 0x7FFFu + ((u >> 16) & 1u)) >> 16;
    return (unsigned short)r;
}
__device__ __forceinline__ float bf2f(unsigned short h) {
    unsigned int u = ((unsigned int)h) << 16;
    return __builtin_bit_cast(float, u);
}
__device__ __forceinline__ float sigmoidf_(float x) {
    return 1.0f / (1.0f + __expf(-x));
}
__device__ __forceinline__ float tanhf_(float x) {
    return 1.0f - 2.0f / (__expf(2.0f * x) + 1.0f);
}

// ---------------- prep: W split ----------------
// Recurrent half -> Wimg, an LDS-image per lt-slice (131072 B):
//   slice lt, chunk j=k>>5 (0..31, 4096B each), row nl (0..63, 64B each), byte (k&31)*2.
// Embedding half -> Wemb hi/lo (row-major [row][k], row = lt*64 + gate*16 + li).
__global__ void prep_w_all(const float* __restrict__ Wf, const float* __restrict__ Wi,
                           const float* __restrict__ Wo, const float* __restrict__ Wc,
                           unsigned short* __restrict__ Wimg,
                           unsigned short* __restrict__ Wemb_hi,
                           unsigned short* __restrict__ Wemb_lo) {
    int idx = blockIdx.x * 256 + threadIdx.x;
    const int total = NG * 2048;  // 8M
    for (; idx < total; idx += gridDim.x * 256) {
        int row = idx >> 11;        // 0..4095
        int col = idx & 2047;       // 0..2047
        int lt   = row >> 6;
        int nl   = row & 63;
        int gate = nl >> 4;
        int l    = lt * 16 + (nl & 15);
        const float* W = (gate == 0) ? Wf : (gate == 1) ? Wi : (gate == 2) ? Wo : Wc;
        float w = W[l * 2048 + col];
        if (col >= 1024) {
            int k = col - 1024;
            size_t byte = (size_t)lt * 131072 + (size_t)(k >> 5) * 4096 + nl * 64 + (k & 31) * 2;
            *(unsigned short*)((char*)Wimg + byte) = f2bf(w);
        } else {
            unsigned short hi = f2bf(w);
            float lo = w - bf2f(hi);
            Wemb_hi[row * 1024 + col] = hi;
            Wemb_lo[row * 1024 + col] = f2bf(lo);
        }
    }
}

// ---------------- prep: emb hi/lo split, padded to 96 rows ----------------
__global__ void prep_emb_split(const float* __restrict__ emb,
                               unsigned short* __restrict__ Eh,
                               unsigned short* __restrict__ El) {
    int idx = blockIdx.x * 256 + threadIdx.x;   // 96*1024 threads
    int v = idx >> 10;
    float w = (v < VV) ? emb[idx] : 0.0f;
    unsigned short hi = f2bf(w);
    Eh[idx] = hi;
    El[idx] = f2bf(w - bf2f(hi));
}

// ---------------- prep: gate_pre2[v][l][gate] via hi/lo MFMA ----------------
__global__ __launch_bounds__(128)
void gate_pre_mfma(const unsigned short* __restrict__ Eh, const unsigned short* __restrict__ El,
                   const unsigned short* __restrict__ Wh, const unsigned short* __restrict__ Wl,
                   const float* __restrict__ bfv, const float* __restrict__ biv,
                   const float* __restrict__ bov, const float* __restrict__ bcv,
                   float* __restrict__ gp2) {
    const int lt   = blockIdx.x;
    const int tid  = threadIdx.x;
    const int lane = tid & 63;
    const int wm   = tid >> 6;
    const int l15  = lane & 15;
    const int kq   = lane >> 4;          // 0..3

    f32x4 acc[3][4];
    #pragma unroll
    for (int mf = 0; mf < 3; ++mf)
        #pragma unroll
        for (int nf = 0; nf < 4; ++nf) acc[mf][nf] = (f32x4){0.f, 0.f, 0.f, 0.f};

    #pragma unroll 2
    for (int ks = 0; ks < 32; ++ks) {
        const int k0 = ks * 32 + kq * 8;
        bf16x8 ah[3], al[3], bh[4], bl[4];
        #pragma unroll
        for (int mf = 0; mf < 3; ++mf) {
            const size_t ao = (size_t)(wm * 48 + mf * 16 + l15) * 1024 + k0;
            ah[mf] = *(const bf16x8*)(Eh + ao);
            al[mf] = *(const bf16x8*)(El + ao);
        }
        #pragma unroll
        for (int nf = 0; nf < 4; ++nf) {
            const size_t bo = (size_t)(lt * 64 + nf * 16 + l15) * 1024 + k0;
            bh[nf] = *(const bf16x8*)(Wh + bo);
            bl[nf] = *(const bf16x8*)(Wl + bo);
        }
        #pragma unroll
        for (int mf = 0; mf < 3; ++mf)
            #pragma unroll
            for (int nf = 0; nf < 4; ++nf) {
                acc[mf][nf] = __builtin_amdgcn_mfma_f32_16x16x32_bf16(ah[mf], bh[nf], acc[mf][nf], 0, 0, 0);
                acc[mf][nf] = __builtin_amdgcn_mfma_f32_16x16x32_bf16(ah[mf], bl[nf], acc[mf][nf], 0, 0, 0);
                acc[mf][nf] = __builtin_amdgcn_mfma_f32_16x16x32_bf16(al[mf], bh[nf], acc[mf][nf], 0, 0, 0);
            }
    }

    const int lgl = lt * 16 + l15;
    #pragma unroll
    for (int nf = 0; nf < 4; ++nf) {
        const float* bias = (nf == 0) ? bfv : (nf == 1) ? biv : (nf == 2) ? bov : bcv;
        const float bv = bias[lgl];
        #pragma unroll
        for (int mf = 0; mf < 3; ++mf)
            #pragma unroll
            for (int r = 0; r < 4; ++r) {
                const int v = wm * 48 + mf * 16 + kq * 4 + r;
                if (v < VV)
                    gp2[((size_t)v * LL + lgl) * 4 + nf] = acc[mf][nf][r] + bv;
            }
    }
}

// ---------------- prep: init h0 (bf16) and c (=0; layout [l][b]) ----------------
__global__ void init_state(const float* __restrict__ h_init,
                           unsigned short* __restrict__ h0, float* __restrict__ c) {
    int idx = blockIdx.x * 256 + threadIdx.x;   // 1024*256 = BB*LL
    h0[idx] = f2bf(h_init[idx]);
    c[idx] = 0.f;                               // zeros: layout-agnostic
}

// ---------------- per-timestep kernel ----------------
// grid 256 (bt=blk>>6, lt=blk&63), 256 threads = 4 waves, wave w: m-rows w*16..w*16+15.
// Issue order (pinned): [x int4, A x32 -> regs, gp x4, c f4] | [stage x32] | quarters.
// Counted vmcnt(24/16/8/0) + 1 barrier per quarter; epilogue fully prefetched.
__global__ __launch_bounds__(256, 1)
void lstm_step3(const unsigned short* __restrict__ Wimg,
                const float* __restrict__ gp2,
                const int* __restrict__ x_t,
                const unsigned short* __restrict__ h_in,
                unsigned short* __restrict__ h_out,
                float* __restrict__ c_ws,        // layout [l*BB + b]
                float* __restrict__ out_t) {
    __shared__ unsigned short wlds_s[65536];   // 128 KiB
    char* wlds = (char*)wlds_s;

    const int tid  = threadIdx.x;
    const int lane = tid & 63;
    const int wv   = tid >> 6;
    const int bt   = blockIdx.x >> 6;
    const int lt   = blockIdx.x & 63;
    const int l15  = lane & 15;
    const int kq   = lane >> 4;

    const int l  = lt * 16 + l15;
    const int b0 = bt * 64 + wv * 16 + kq * 4;   // this thread's 4 batch rows

    // ---- prefetch x, A (h rows), gate_pre, c — all before staging ----
    const int4 xt4 = *(const int4*)(x_t + b0);

    const char* aptr = (const char*)h_in + (size_t)(bt * 64 + wv * 16 + l15) * 2048 + kq * 16;
    bf16x8 a[32];
    #pragma unroll
    for (int ks = 0; ks < 32; ++ks)
        a[ks] = *(const bf16x8*)(aptr + ks * 64);

    float4 gpv[4];
    {
        const int vr[4] = {xt4.x, xt4.y, xt4.z, xt4.w};
        #pragma unroll
        for (int r = 0; r < 4; ++r)
            gpv[r] = *(const float4*)(gp2 + ((size_t)vr[r] * LL + l) * 4);
    }
    float4 cv = *(const float4*)(c_ws + (size_t)l * BB + b0);

    __builtin_amdgcn_sched_barrier(0);

    // ---- issue all 32 B-stage loads (1 KB per wave-instr, linear LDS dest) ----
    const char* wsrc = (const char*)Wimg + (size_t)lt * 131072 + tid * 16;
    #pragma unroll
    for (int j = 0; j < 32; ++j) {
        __builtin_amdgcn_global_load_lds((gu32*)(wsrc + j * 4096),
                                         (lu32*)(wlds + j * 4096 + wv * 1024),
                                         16, 0, 0);
    }
    __builtin_amdgcn_sched_barrier(0);

    // B frag base: chunk ks at ks*4096, row (nf*16+l15)*64, lane k-slot kq*16
    const char* bbase = wlds + l15 * 64 + kq * 16;

    f32x4 acc[4];
    #pragma unroll
    for (int nf = 0; nf < 4; ++nf) acc[nf] = (f32x4){0.f, 0.f, 0.f, 0.f};

    #define QUARTER(q, NW)                                                       \
        asm volatile("s_waitcnt vmcnt(" #NW ")" ::: "memory");                   \
        __builtin_amdgcn_s_barrier();                                            \
        _Pragma("unroll") for (int ki = 0; ki < 8; ++ki) {                       \
            const int ks = (q) * 8 + ki;                                         \
            const char* bc = bbase + ks * 4096;                                  \
            bf16x8 bw0 = *(const bf16x8*)(bc);                                   \
            bf16x8 bw1 = *(const bf16x8*)(bc + 1024);                            \
            bf16x8 bw2 = *(const bf16x8*)(bc + 2048);                            \
            bf16x8 bw3 = *(const bf16x8*)(bc + 3072);                            \
            acc[0] = __builtin_amdgcn_mfma_f32_16x16x32_bf16(a[ks], bw0, acc[0], 0, 0, 0); \
            acc[1] = __builtin_amdgcn_mfma_f32_16x16x32_bf16(a[ks], bw1, acc[1], 0, 0, 0); \
            acc[2] = __builtin_amdgcn_mfma_f32_16x16x32_bf16(a[ks], bw2, acc[2], 0, 0, 0); \
            acc[3] = __builtin_amdgcn_mfma_f32_16x16x32_bf16(a[ks], bw3, acc[3], 0, 0, 0); \
        }

    QUARTER(0, 24)
    QUARTER(1, 16)
    QUARTER(2, 8)
    QUARTER(3, 0)
    #undef QUARTER

    // ---- epilogue: all operands in registers; acc[nf] = gates f,i,o,c~ ----
    float cnew[4], hnew[4];
    {
        const float cold[4] = {cv.x, cv.y, cv.z, cv.w};
        #pragma unroll
        for (int r = 0; r < 4; ++r) {
            const float gf = acc[0][r] + gpv[r].x;
            const float gi = acc[1][r] + gpv[r].y;
            const float go = acc[2][r] + gpv[r].z;
            const float gc = acc[3][r] + gpv[r].w;
            const float cn = sigmoidf_(gf) * cold[r] + sigmoidf_(gi) * tanhf_(gc);
            hnew[r] = sigmoidf_(go) * tanhf_(cn);
            cnew[r] = cn;
        }
    }
    *(float4*)(c_ws + (size_t)l * BB + b0) = (float4){cnew[0], cnew[1], cnew[2], cnew[3]};
    #pragma unroll
    for (int r = 0; r < 4; ++r) {
        const size_t off = (size_t)(b0 + r) * LL + l;
        out_t[off] = hnew[r];
        h_out[off] = f2bf(hnew[r]);
    }
}

// ---------------- launch ----------------
extern "C" void kernel_launch(void* const* d_in, const int* in_sizes, int n_in,
                              void* d_out, int out_size, void* d_ws, size_t ws_size,
                              hipStream_t stream) {
    const int*   x      = (const int*)d_in[0];
    const float* h_init = (const float*)d_in[1];
    const float* emb    = (const float*)d_in[2];
    const float* Wf     = (const float*)d_in[3];
    const float* bfv    = (const float*)d_in[4];
    const float* Wi     = (const float*)d_in[5];
    const float* biv    = (const float*)d_in[6];
    const float* Wo     = (const float*)d_in[7];
    const float* bov    = (const float*)d_in[8];
    const float* Wc     = (const float*)d_in[9];
    const float* bcv    = (const float*)d_in[10];
    float* out = (float*)d_out;

    char* ws = (char*)d_ws;
    unsigned short* Wimg    = (unsigned short*)(ws);                 // 8 MB
    unsigned short* Wemb_hi = (unsigned short*)(ws + 8388608);       // 8 MB
    unsigned short* Wemb_lo = (unsigned short*)(ws + 16777216);      // 8 MB
    unsigned short* Eh      = (unsigned short*)(ws + 25165824);      // 192 KB
    unsigned short* El      = (unsigned short*)(ws + 25362432);      // 192 KB
    float*          gp2     = (float*)(ws + 25559040);               // 1.5 MB
    float*          c_ws    = (float*)(ws + 27131904);               // 1 MB
    unsigned short* hb0     = (unsigned short*)(ws + 28180480);      // 512 KB
    unsigned short* hb1     = (unsigned short*)(ws + 28704768);      // 512 KB

    prep_w_all<<<4096, 256, 0, stream>>>(Wf, Wi, Wo, Wc, Wimg, Wemb_hi, Wemb_lo);
    prep_emb_split<<<384, 256, 0, stream>>>(emb, Eh, El);
    gate_pre_mfma<<<64, 128, 0, stream>>>(Eh, El, Wemb_hi, Wemb_lo,
                                          bfv, biv, bov, bcv, gp2);
    init_state<<<1024, 256, 0, stream>>>(h_init, hb0, c_ws);

    unsigned short* hin = hb0;
    unsigned short* hout = hb1;
    for (int t = 0; t < TT; ++t) {
        lstm_step3<<<256, 256, 0, stream>>>(Wimg, gp2, x + t * BB,
                                            hin, hout, c_ws,
                                            out + (size_t)t * BB * LL);
        unsigned short* tmp = hin; hin = hout; hout = tmp;
    }
}